// Round 9
// baseline (120.209 us; speedup 1.0000x reference)
//
#include <hip/hip_runtime.h>
#include <hip/hip_bf16.h>

// Problem constants: x is [16, 256, 128, 128] float32.
#define B 16
#define C 256
#define H 128
#define W 128
#define HW (H * W)            // 16384
#define BC (B * C)            // 4096
#define KSEL 26               // round(0.1 * 256)
#define NPART (BC * 2)        // two partial-stat blocks per channel

typedef float v4f __attribute__((ext_vector_type(4)));

// ordered-int mapping for monotone binary search over float bits
__device__ __forceinline__ unsigned ordf(float x) {
    unsigned u = __float_as_uint(x);
    return (u & 0x80000000u) ? ~u : (u | 0x80000000u);
}
__device__ __forceinline__ float unordf(unsigned k) {
    unsigned u = (k & 0x80000000u) ? (k & 0x7fffffffu) : ~k;
    return __uint_as_float(u);
}

// -------------------- Kernel 1: fused partial score + copy --------------------
// TWO blocks (256 threads each) per channel; each streams 32 KB with the
// R5/R8-proven simple grid-stride loop (VGPR ~16, high occupancy). Bin
// thresholds (thr[k] = smallest float with rintf(tanhf(x)*10) >= k) are
// derived IN-BLOCK by threads 0..10 via binary search over ordered float bits
// using the device's own tanhf/rintf -> compare-based binning is bit-identical
// to direct evaluation (tanhf monotone). Emits raw partials {cge[11], sum,
// sumsq}; entropy/var epilogue deferred to select_kernel.
__global__ __launch_bounds__(256) void score_copy_kernel(const float* __restrict__ x,
                                                         double* __restrict__ psum,
                                                         double* __restrict__ psq,
                                                         unsigned* __restrict__ pg,
                                                         float* __restrict__ out) {
    const int p = blockIdx.x;      // 0 .. NPART-1
    const int bc = p >> 1;
    const int half = p & 1;
    const int tid = threadIdx.x;
    const v4f* xv = ((const v4f*)(x + (size_t)bc * HW)) + half * (HW / 8);
    v4f* ov = ((v4f*)(out + (size_t)bc * HW)) + half * (HW / 8);

    __shared__ float sthr[11];
    if (tid < 11) {
        unsigned lo = ordf(-2.0f), hi = ordf(4.0f);
        while (lo < hi) {
            unsigned mid = lo + (hi - lo) / 2;
            float q = rintf(tanhf(unordf(mid)) * 10.0f);
            if (q >= (float)tid) hi = mid; else lo = mid + 1;
        }
        sthr[tid] = unordf(lo);
    }
    __syncthreads();

    float t[11];
#pragma unroll
    for (int k = 0; k < 11; ++k) t[k] = sthr[k];

    unsigned cge[11];
#pragma unroll
    for (int k = 0; k < 11; ++k) cge[k] = 0;
    double sum = 0.0, sumsq = 0.0;

    for (int i = tid; i < HW / 8; i += 256) {
        v4f v = xv[i];
        __builtin_nontemporal_store(v, &ov[i]);
        float s4 = (v.x + v.y) + (v.z + v.w);
        float q4 = fmaf(v.w, v.w, fmaf(v.z, v.z, fmaf(v.y, v.y, v.x * v.x)));
        sum += (double)s4;
        sumsq += (double)q4;
        float arr[4] = {v.x, v.y, v.z, v.w};
#pragma unroll
        for (int j = 0; j < 4; ++j) {
            float f = arr[j];
#pragma unroll
            for (int k = 0; k < 11; ++k)
                cge[k] += (unsigned)__popcll(__ballot(f >= t[k]));
        }
    }

    // cge[] is wave-uniform. Reduce sum/sumsq across the wave.
#pragma unroll
    for (int off = 32; off > 0; off >>= 1) {
        sum += __shfl_down(sum, off);
        sumsq += __shfl_down(sumsq, off);
    }

    __shared__ unsigned sh_cge[4][11];
    __shared__ double sh_sum[4], sh_sq[4];
    const int wave = tid >> 6;
    const int lane = tid & 63;
    if (lane == 0) {
#pragma unroll
        for (int k = 0; k < 11; ++k) sh_cge[wave][k] = cge[k];
        sh_sum[wave] = sum;
        sh_sq[wave] = sumsq;
    }
    __syncthreads();

    if (tid == 0) {
#pragma unroll
        for (int k = 0; k < 11; ++k)
            pg[p * 11 + k] = sh_cge[0][k] + sh_cge[1][k] + sh_cge[2][k] + sh_cge[3][k];
        psum[p] = sh_sum[0] + sh_sum[1] + sh_sum[2] + sh_sum[3];
        psq[p] = sh_sq[0] + sh_sq[1] + sh_sq[2] + sh_sq[3];
    }
}

// -------------------- Kernel 2: finish scores + top-k -> compact list --------------------
// One block per batch; thread t owns channel t: combine the two partials,
// compute entropy + 2/(var+eps), then rank-by-counting with stable-argsort
// tie semantics. rank < KSEL gives a unique compact slot.
__global__ __launch_bounds__(256) void select_kernel(const double* __restrict__ psum,
                                                     const double* __restrict__ psq,
                                                     const unsigned* __restrict__ pg,
                                                     int* __restrict__ compact) {
    __shared__ double s[C];
    const int b = blockIdx.x;
    const int t = threadIdx.x;
    const int p0 = (b * C + t) * 2;

    unsigned g[11];
#pragma unroll
    for (int k = 0; k < 11; ++k) g[k] = pg[p0 * 11 + k] + pg[(p0 + 1) * 11 + k];
    double sum = psum[p0] + psum[p0 + 1];
    double sq = psq[p0] + psq[p0 + 1];

    double ent = 0.0;
    double inv = 1.0 / (double)g[0];
#pragma unroll
    for (int k = 0; k < 11; ++k) {
        unsigned ck = (k < 10) ? (g[k] - g[k + 1]) : g[10];
        double pk = (double)ck * inv;
        if (pk > 0.0) ent -= pk * log(pk);
    }
    const double L = (double)HW;
    double var = (sq - sum * sum / L) / (L - 1.0);
    s[t] = ent + 2.0 / (var + 1e-7);
    __syncthreads();

    const double mine = s[t];
    int rank = 0;
    for (int j = 0; j < C; ++j) {
        double v = s[j];
        rank += (v > mine) || (v == mine && j < t);
    }
    if (rank < KSEL) compact[b * KSEL + rank] = t;
}

// -------------------- Kernel 3: Laplace rewrite of selected channels --------------------
// Exactly B*KSEL channels; 4 blocks per channel (32 rows each), one barrier.
#define LROWS 32
#define PERCH (H / LROWS)   // 4
__global__ __launch_bounds__(256) void laplace_kernel(const float* __restrict__ x,
                                                      const int* __restrict__ compact,
                                                      float* __restrict__ out) {
    const int blk = blockIdx.x;
    const int b = blk / (KSEL * PERCH);
    const int r0 = blk % (KSEL * PERCH);
    const int slot = r0 / PERCH;
    const int chunk = r0 % PERCH;
    const int c = compact[b * KSEL + slot];
    const size_t base = (size_t)(b * C + c) * HW;
    const float* xc = x + base;
    float* oc = out + base;
    const int h0 = chunk * LROWS;

    __shared__ float tile[LROWS + 2][W];
    for (int i = threadIdx.x; i < (LROWS + 2) * (W / 4); i += 256) {
        int rr = i >> 5;       // / (W/4)
        int cv = i & 31;       // % (W/4)
        int h = h0 - 1 + rr;
        v4f v = (v4f)(0.f);
        if (h >= 0 && h < H) v = ((const v4f*)(xc + h * W))[cv];
        ((v4f*)tile[rr])[cv] = v;
    }
    __syncthreads();

    for (int i = threadIdx.x; i < LROWS * W; i += 256) {
        int rr = i >> 7;          // / W
        int col = i & (W - 1);    // % W
        int tr = rr + 1;
        float cc = tile[tr][col];
        float up = tile[tr - 1][col];
        float dn = tile[tr + 1][col];
        float lf = 0.f, rt = 0.f, ul = 0.f, ur = 0.f, dl = 0.f, dr = 0.f;
        if (col > 0) {
            lf = tile[tr][col - 1];
            ul = tile[tr - 1][col - 1];
            dl = tile[tr + 1][col - 1];
        }
        if (col < W - 1) {
            rt = tile[tr][col + 1];
            ur = tile[tr - 1][col + 1];
            dr = tile[tr + 1][col + 1];
        }
        float res = 8.0f * cc - (up + dn + lf + rt + ul + ur + dl + dr);
        __builtin_nontemporal_store(res, &oc[(h0 + rr) * W + col]);
    }
}

extern "C" void kernel_launch(void* const* d_in, const int* in_sizes, int n_in,
                              void* d_out, int out_size, void* d_ws, size_t ws_size,
                              hipStream_t stream) {
    const float* x = (const float*)d_in[0];
    float* out = (float*)d_out;

    double* psum = (double*)d_ws;                           // 8192 doubles
    double* psq = psum + NPART;                             // 8192 doubles
    int* compact = (int*)(psq + NPART);                     // 416 ints
    unsigned* pg = (unsigned*)(compact + B * KSEL);         // 8192*11 uints

    score_copy_kernel<<<NPART, 256, 0, stream>>>(x, psum, psq, pg, out);
    select_kernel<<<B, 256, 0, stream>>>(psum, psq, pg, compact);
    laplace_kernel<<<B * KSEL * PERCH, 256, 0, stream>>>(x, compact, out);
}

// Round 10
// 112.690 us; speedup vs baseline: 1.0667x; 1.0667x over previous
//
#include <hip/hip_runtime.h>
#include <hip/hip_bf16.h>

// Problem constants: x is [16, 256, 128, 128] float32.
#define B 16
#define C 256
#define H 128
#define W 128
#define HW (H * W)            // 16384
#define BC (B * C)            // 4096
#define KSEL 26               // round(0.1 * 256)
#define NPART (BC * 2)        // two partial-stat blocks per channel

typedef float v4f __attribute__((ext_vector_type(4)));

// ordered-int mapping for monotone binary search over float bits
__device__ __forceinline__ unsigned ordf(float x) {
    unsigned u = __float_as_uint(x);
    return (u & 0x80000000u) ? ~u : (u | 0x80000000u);
}
__device__ __forceinline__ float unordf(unsigned k) {
    unsigned u = (k & 0x80000000u) ? (k & 0x7fffffffu) : ~k;
    return __uint_as_float(u);
}

// -------------------- Kernel 0: derive exact bin thresholds --------------------
// thr[k] = smallest float x in [-2,4] with rintf(tanhf(x)*10.f) >= k, k=0..10.
// Device's own tanhf/rintf -> compare-based binning is bit-identical (monotone).
// Separate tiny kernel: its ~1 us cost is paid ONCE, not per-block (R9 lesson).
__global__ void init_thresholds(float* __restrict__ thr) {
    int k = threadIdx.x;
    if (k > 10) return;
    unsigned lo = ordf(-2.0f), hi = ordf(4.0f);
    while (lo < hi) {
        unsigned mid = lo + (hi - lo) / 2;
        float xm = unordf(mid);
        float q = rintf(tanhf(xm) * 10.0f);
        if (q >= (float)k) hi = mid; else lo = mid + 1;
    }
    thr[k] = unordf(lo);
}

// -------------------- Kernel 1: fused partial score + copy --------------------
// TWO blocks (256 threads each) per channel; each streams 32 KB with the
// R5/R8-proven simple grid-stride loop (VGPR ~16, high occupancy). Emits raw
// partials {cge[11], sum, sumsq}; entropy/var epilogue deferred to select.
__global__ __launch_bounds__(256) void score_copy_kernel(const float* __restrict__ x,
                                                         const float* __restrict__ thr,
                                                         double* __restrict__ psum,
                                                         double* __restrict__ psq,
                                                         unsigned* __restrict__ pg,
                                                         float* __restrict__ out) {
    const int p = blockIdx.x;      // 0 .. NPART-1
    const int bc = p >> 1;
    const int half = p & 1;
    const int tid = threadIdx.x;
    const v4f* xv = ((const v4f*)(x + (size_t)bc * HW)) + half * (HW / 8);
    v4f* ov = ((v4f*)(out + (size_t)bc * HW)) + half * (HW / 8);

    float t[11];
#pragma unroll
    for (int k = 0; k < 11; ++k) t[k] = thr[k];

    unsigned cge[11];
#pragma unroll
    for (int k = 0; k < 11; ++k) cge[k] = 0;
    double sum = 0.0, sumsq = 0.0;

    for (int i = tid; i < HW / 8; i += 256) {
        v4f v = xv[i];
        __builtin_nontemporal_store(v, &ov[i]);
        float s4 = (v.x + v.y) + (v.z + v.w);
        float q4 = fmaf(v.w, v.w, fmaf(v.z, v.z, fmaf(v.y, v.y, v.x * v.x)));
        sum += (double)s4;
        sumsq += (double)q4;
        float arr[4] = {v.x, v.y, v.z, v.w};
#pragma unroll
        for (int j = 0; j < 4; ++j) {
            float f = arr[j];
#pragma unroll
            for (int k = 0; k < 11; ++k)
                cge[k] += (unsigned)__popcll(__ballot(f >= t[k]));
        }
    }

    // cge[] is wave-uniform. Reduce sum/sumsq across the wave.
#pragma unroll
    for (int off = 32; off > 0; off >>= 1) {
        sum += __shfl_down(sum, off);
        sumsq += __shfl_down(sumsq, off);
    }

    __shared__ unsigned sh_cge[4][11];
    __shared__ double sh_sum[4], sh_sq[4];
    const int wave = tid >> 6;
    const int lane = tid & 63;
    if (lane == 0) {
#pragma unroll
        for (int k = 0; k < 11; ++k) sh_cge[wave][k] = cge[k];
        sh_sum[wave] = sum;
        sh_sq[wave] = sumsq;
    }
    __syncthreads();

    if (tid == 0) {
#pragma unroll
        for (int k = 0; k < 11; ++k)
            pg[p * 11 + k] = sh_cge[0][k] + sh_cge[1][k] + sh_cge[2][k] + sh_cge[3][k];
        psum[p] = sh_sum[0] + sh_sum[1] + sh_sum[2] + sh_sum[3];
        psq[p] = sh_sq[0] + sh_sq[1] + sh_sq[2] + sh_sq[3];
    }
}

// -------------------- Kernel 2: finish scores + top-k -> compact list --------------------
// One block per batch; thread t owns channel t: combine the two partials,
// compute entropy + 2/(var+eps), then rank-by-counting with stable-argsort
// tie semantics. rank < KSEL gives a unique compact slot.
__global__ __launch_bounds__(256) void select_kernel(const double* __restrict__ psum,
                                                     const double* __restrict__ psq,
                                                     const unsigned* __restrict__ pg,
                                                     int* __restrict__ compact) {
    __shared__ double s[C];
    const int b = blockIdx.x;
    const int t = threadIdx.x;
    const int p0 = (b * C + t) * 2;

    unsigned g[11];
#pragma unroll
    for (int k = 0; k < 11; ++k) g[k] = pg[p0 * 11 + k] + pg[(p0 + 1) * 11 + k];
    double sum = psum[p0] + psum[p0 + 1];
    double sq = psq[p0] + psq[p0 + 1];

    double ent = 0.0;
    double inv = 1.0 / (double)g[0];
#pragma unroll
    for (int k = 0; k < 11; ++k) {
        unsigned ck = (k < 10) ? (g[k] - g[k + 1]) : g[10];
        double pk = (double)ck * inv;
        if (pk > 0.0) ent -= pk * log(pk);
    }
    const double L = (double)HW;
    double var = (sq - sum * sum / L) / (L - 1.0);
    s[t] = ent + 2.0 / (var + 1e-7);
    __syncthreads();

    const double mine = s[t];
    int rank = 0;
    for (int j = 0; j < C; ++j) {
        double v = s[j];
        rank += (v > mine) || (v == mine && j < t);
    }
    if (rank < KSEL) compact[b * KSEL + rank] = t;
}

// -------------------- Kernel 3: Laplace rewrite of selected channels --------------------
// Exactly B*KSEL channels; 8 blocks per channel (16 rows each), one barrier.
#define LROWS 16
#define PERCH (H / LROWS)   // 8
__global__ __launch_bounds__(256) void laplace_kernel(const float* __restrict__ x,
                                                      const int* __restrict__ compact,
                                                      float* __restrict__ out) {
    const int blk = blockIdx.x;
    const int b = blk / (KSEL * PERCH);
    const int r0 = blk % (KSEL * PERCH);
    const int slot = r0 / PERCH;
    const int chunk = r0 % PERCH;
    const int c = compact[b * KSEL + slot];
    const size_t base = (size_t)(b * C + c) * HW;
    const float* xc = x + base;
    float* oc = out + base;
    const int h0 = chunk * LROWS;

    __shared__ float tile[LROWS + 2][W];
    for (int i = threadIdx.x; i < (LROWS + 2) * (W / 4); i += 256) {
        int rr = i >> 5;       // / (W/4)
        int cv = i & 31;       // % (W/4)
        int h = h0 - 1 + rr;
        v4f v = (v4f)(0.f);
        if (h >= 0 && h < H) v = ((const v4f*)(xc + h * W))[cv];
        ((v4f*)tile[rr])[cv] = v;
    }
    __syncthreads();

    for (int i = threadIdx.x; i < LROWS * W; i += 256) {
        int rr = i >> 7;          // / W
        int col = i & (W - 1);    // % W
        int tr = rr + 1;
        float cc = tile[tr][col];
        float up = tile[tr - 1][col];
        float dn = tile[tr + 1][col];
        float lf = 0.f, rt = 0.f, ul = 0.f, ur = 0.f, dl = 0.f, dr = 0.f;
        if (col > 0) {
            lf = tile[tr][col - 1];
            ul = tile[tr - 1][col - 1];
            dl = tile[tr + 1][col - 1];
        }
        if (col < W - 1) {
            rt = tile[tr][col + 1];
            ur = tile[tr - 1][col + 1];
            dr = tile[tr + 1][col + 1];
        }
        float res = 8.0f * cc - (up + dn + lf + rt + ul + ur + dl + dr);
        __builtin_nontemporal_store(res, &oc[(h0 + rr) * W + col]);
    }
}

extern "C" void kernel_launch(void* const* d_in, const int* in_sizes, int n_in,
                              void* d_out, int out_size, void* d_ws, size_t ws_size,
                              hipStream_t stream) {
    const float* x = (const float*)d_in[0];
    float* out = (float*)d_out;

    double* psum = (double*)d_ws;                           // 8192 doubles
    double* psq = psum + NPART;                             // 8192 doubles
    int* compact = (int*)(psq + NPART);                     // 416 ints
    float* thr = (float*)(compact + B * KSEL);              // 11 floats
    unsigned* pg = (unsigned*)(thr + 12);                   // 8192*11 uints

    init_thresholds<<<1, 64, 0, stream>>>(thr);
    score_copy_kernel<<<NPART, 256, 0, stream>>>(x, thr, psum, psq, pg, out);
    select_kernel<<<B, 256, 0, stream>>>(psum, psq, pg, compact);
    laplace_kernel<<<B * KSEL * PERCH, 256, 0, stream>>>(x, compact, out);
}

// Round 11
// 112.264 us; speedup vs baseline: 1.0708x; 1.0038x over previous
//
#include <hip/hip_runtime.h>
#include <hip/hip_bf16.h>

// Problem constants: x is [16, 256, 128, 128] float32.
#define B 16
#define C 256
#define H 128
#define W 128
#define HW (H * W)            // 16384
#define BC (B * C)            // 4096
#define KSEL 26               // round(0.1 * 256)
#define NPART (BC * 2)        // two partial-stat blocks per channel

typedef float v4f __attribute__((ext_vector_type(4)));

// ordered-int mapping for monotone binary search over float bits
__device__ __forceinline__ unsigned ordf(float x) {
    unsigned u = __float_as_uint(x);
    return (u & 0x80000000u) ? ~u : (u | 0x80000000u);
}
__device__ __forceinline__ float unordf(unsigned k) {
    unsigned u = (k & 0x80000000u) ? (k & 0x7fffffffu) : ~k;
    return __uint_as_float(u);
}

// -------------------- Kernel 0: derive exact bin thresholds --------------------
// thr[k] = smallest float x in [-2,4] with rintf(tanhf(x)*10.f) >= k, k=0..10.
// Device's own tanhf/rintf -> compare-based binning is bit-identical (monotone).
// Separate tiny kernel: its ~1 us cost is paid ONCE, not per-block (R9 lesson).
__global__ void init_thresholds(float* __restrict__ thr) {
    int k = threadIdx.x;
    if (k > 10) return;
    unsigned lo = ordf(-2.0f), hi = ordf(4.0f);
    while (lo < hi) {
        unsigned mid = lo + (hi - lo) / 2;
        float xm = unordf(mid);
        float q = rintf(tanhf(xm) * 10.0f);
        if (q >= (float)k) hi = mid; else lo = mid + 1;
    }
    thr[k] = unordf(lo);
}

// -------------------- Kernel 1: fused partial score + copy --------------------
// TWO blocks (256 threads each) per channel; each streams 32 KB. R11 change
// (single, isolated): unroll x2 -- TWO independent v4f loads issued per
// iteration before processing either, doubling per-wave bytes in flight
// (1 KiB -> 2 KiB; ~36 KiB/CU vs ~12 KiB BW-delay product) at ~+8 VGPR.
// Emits raw partials {cge[11], sum, sumsq}; epilogue deferred to select.
__global__ __launch_bounds__(256) void score_copy_kernel(const float* __restrict__ x,
                                                         const float* __restrict__ thr,
                                                         double* __restrict__ psum,
                                                         double* __restrict__ psq,
                                                         unsigned* __restrict__ pg,
                                                         float* __restrict__ out) {
    const int p = blockIdx.x;      // 0 .. NPART-1
    const int bc = p >> 1;
    const int half = p & 1;
    const int tid = threadIdx.x;
    const v4f* xv = ((const v4f*)(x + (size_t)bc * HW)) + half * (HW / 8);
    v4f* ov = ((v4f*)(out + (size_t)bc * HW)) + half * (HW / 8);

    float t[11];
#pragma unroll
    for (int k = 0; k < 11; ++k) t[k] = thr[k];

    unsigned cge[11];
#pragma unroll
    for (int k = 0; k < 11; ++k) cge[k] = 0;
    double sum = 0.0, sumsq = 0.0;

    // 2048 v4f per block; stride 512 -> 4 iterations x 2 independent loads
    for (int i = tid; i < HW / 8; i += 512) {
        v4f v0 = xv[i];
        v4f v1 = xv[i + 256];

        __builtin_nontemporal_store(v0, &ov[i]);
        __builtin_nontemporal_store(v1, &ov[i + 256]);

        float s4 = ((v0.x + v0.y) + (v0.z + v0.w)) + ((v1.x + v1.y) + (v1.z + v1.w));
        float q4 = fmaf(v0.w, v0.w, fmaf(v0.z, v0.z, fmaf(v0.y, v0.y, v0.x * v0.x)));
        q4 = fmaf(v1.w, v1.w, fmaf(v1.z, v1.z, fmaf(v1.y, v1.y, fmaf(v1.x, v1.x, q4))));
        sum += (double)s4;
        sumsq += (double)q4;

        float arr[8] = {v0.x, v0.y, v0.z, v0.w, v1.x, v1.y, v1.z, v1.w};
#pragma unroll
        for (int j = 0; j < 8; ++j) {
            float f = arr[j];
#pragma unroll
            for (int k = 0; k < 11; ++k)
                cge[k] += (unsigned)__popcll(__ballot(f >= t[k]));
        }
    }

    // cge[] is wave-uniform. Reduce sum/sumsq across the wave.
#pragma unroll
    for (int off = 32; off > 0; off >>= 1) {
        sum += __shfl_down(sum, off);
        sumsq += __shfl_down(sumsq, off);
    }

    __shared__ unsigned sh_cge[4][11];
    __shared__ double sh_sum[4], sh_sq[4];
    const int wave = tid >> 6;
    const int lane = tid & 63;
    if (lane == 0) {
#pragma unroll
        for (int k = 0; k < 11; ++k) sh_cge[wave][k] = cge[k];
        sh_sum[wave] = sum;
        sh_sq[wave] = sumsq;
    }
    __syncthreads();

    if (tid == 0) {
#pragma unroll
        for (int k = 0; k < 11; ++k)
            pg[p * 11 + k] = sh_cge[0][k] + sh_cge[1][k] + sh_cge[2][k] + sh_cge[3][k];
        psum[p] = sh_sum[0] + sh_sum[1] + sh_sum[2] + sh_sum[3];
        psq[p] = sh_sq[0] + sh_sq[1] + sh_sq[2] + sh_sq[3];
    }
}

// -------------------- Kernel 2: finish scores + top-k -> compact list --------------------
// One block per batch; thread t owns channel t: combine the two partials,
// compute entropy + 2/(var+eps), then rank-by-counting with stable-argsort
// tie semantics. rank < KSEL gives a unique compact slot.
__global__ __launch_bounds__(256) void select_kernel(const double* __restrict__ psum,
                                                     const double* __restrict__ psq,
                                                     const unsigned* __restrict__ pg,
                                                     int* __restrict__ compact) {
    __shared__ double s[C];
    const int b = blockIdx.x;
    const int t = threadIdx.x;
    const int p0 = (b * C + t) * 2;

    unsigned g[11];
#pragma unroll
    for (int k = 0; k < 11; ++k) g[k] = pg[p0 * 11 + k] + pg[(p0 + 1) * 11 + k];
    double sum = psum[p0] + psum[p0 + 1];
    double sq = psq[p0] + psq[p0 + 1];

    double ent = 0.0;
    double inv = 1.0 / (double)g[0];
#pragma unroll
    for (int k = 0; k < 11; ++k) {
        unsigned ck = (k < 10) ? (g[k] - g[k + 1]) : g[10];
        double pk = (double)ck * inv;
        if (pk > 0.0) ent -= pk * log(pk);
    }
    const double L = (double)HW;
    double var = (sq - sum * sum / L) / (L - 1.0);
    s[t] = ent + 2.0 / (var + 1e-7);
    __syncthreads();

    const double mine = s[t];
    int rank = 0;
    for (int j = 0; j < C; ++j) {
        double v = s[j];
        rank += (v > mine) || (v == mine && j < t);
    }
    if (rank < KSEL) compact[b * KSEL + rank] = t;
}

// -------------------- Kernel 3: Laplace rewrite of selected channels --------------------
// Exactly B*KSEL channels; 8 blocks per channel (16 rows each), one barrier.
#define LROWS 16
#define PERCH (H / LROWS)   // 8
__global__ __launch_bounds__(256) void laplace_kernel(const float* __restrict__ x,
                                                      const int* __restrict__ compact,
                                                      float* __restrict__ out) {
    const int blk = blockIdx.x;
    const int b = blk / (KSEL * PERCH);
    const int r0 = blk % (KSEL * PERCH);
    const int slot = r0 / PERCH;
    const int chunk = r0 % PERCH;
    const int c = compact[b * KSEL + slot];
    const size_t base = (size_t)(b * C + c) * HW;
    const float* xc = x + base;
    float* oc = out + base;
    const int h0 = chunk * LROWS;

    __shared__ float tile[LROWS + 2][W];
    for (int i = threadIdx.x; i < (LROWS + 2) * (W / 4); i += 256) {
        int rr = i >> 5;       // / (W/4)
        int cv = i & 31;       // % (W/4)
        int h = h0 - 1 + rr;
        v4f v = (v4f)(0.f);
        if (h >= 0 && h < H) v = ((const v4f*)(xc + h * W))[cv];
        ((v4f*)tile[rr])[cv] = v;
    }
    __syncthreads();

    for (int i = threadIdx.x; i < LROWS * W; i += 256) {
        int rr = i >> 7;          // / W
        int col = i & (W - 1);    // % W
        int tr = rr + 1;
        float cc = tile[tr][col];
        float up = tile[tr - 1][col];
        float dn = tile[tr + 1][col];
        float lf = 0.f, rt = 0.f, ul = 0.f, ur = 0.f, dl = 0.f, dr = 0.f;
        if (col > 0) {
            lf = tile[tr][col - 1];
            ul = tile[tr - 1][col - 1];
            dl = tile[tr + 1][col - 1];
        }
        if (col < W - 1) {
            rt = tile[tr][col + 1];
            ur = tile[tr - 1][col + 1];
            dr = tile[tr + 1][col + 1];
        }
        float res = 8.0f * cc - (up + dn + lf + rt + ul + ur + dl + dr);
        __builtin_nontemporal_store(res, &oc[(h0 + rr) * W + col]);
    }
}

extern "C" void kernel_launch(void* const* d_in, const int* in_sizes, int n_in,
                              void* d_out, int out_size, void* d_ws, size_t ws_size,
                              hipStream_t stream) {
    const float* x = (const float*)d_in[0];
    float* out = (float*)d_out;

    double* psum = (double*)d_ws;                           // 8192 doubles
    double* psq = psum + NPART;                             // 8192 doubles
    int* compact = (int*)(psq + NPART);                     // 416 ints
    float* thr = (float*)(compact + B * KSEL);              // 11 floats
    unsigned* pg = (unsigned*)(thr + 12);                   // 8192*11 uints

    init_thresholds<<<1, 64, 0, stream>>>(thr);
    score_copy_kernel<<<NPART, 256, 0, stream>>>(x, thr, psum, psq, pg, out);
    select_kernel<<<B, 256, 0, stream>>>(psum, psq, pg, compact);
    laplace_kernel<<<B * KSEL * PERCH, 256, 0, stream>>>(x, compact, out);
}